// Round 5
// baseline (684.007 us; speedup 1.0000x reference)
//
#include <hip/hip_runtime.h>
#include <hip/hip_bf16.h>

// Problem constants
constexpr int kB  = 4;
constexpr int kS  = 1024;
constexpr int kD  = 2048;
constexpr int kH  = 32;
constexpr int kKV = 8;
constexpr int kHD = 64;

constexpr float kNegBig = -30000.0f;  // finite sentinel: no inf/overflow paths

typedef __attribute__((ext_vector_type(8))) short short8;   // 8 bf16 (4 VGPRs)
typedef __attribute__((ext_vector_type(4))) float floatx4;  // MFMA C/D

static __device__ __forceinline__ float bf2f(short v) {
    unsigned int u = ((unsigned int)(unsigned short)v) << 16;
    return __builtin_bit_cast(float, u);
}
static __device__ __forceinline__ short f2bf(float f) {
    unsigned int u = __builtin_bit_cast(unsigned int, f);
    unsigned int lsb = (u >> 16) & 1u;
    u += 0x7fffu + lsb;                       // round-to-nearest-even
    return (short)(u >> 16);
}

// fp32 -> bf16, vectorized x4. n4 = element_count/4.
__global__ void cast_f2b(const float* __restrict__ in, short* __restrict__ outp, int n4) {
    int gid = blockIdx.x * blockDim.x + threadIdx.x;
    if (gid >= n4) return;
    float4 v = ((const float4*)in)[gid];
    short4 o;
    o.x = f2bf(v.x); o.y = f2bf(v.y); o.z = f2bf(v.z); o.w = f2bf(v.w);
    ((short4*)outp)[gid] = o;
}

// C[M,N] = A[M,K] * B[N,K]^T, bf16 in, fp32 acc, bf16 out.
// Block = 4 waves; each wave owns a 64x64 tile (2x2 wave grid -> 128x128/block).
__global__ __launch_bounds__(256) void gemm_bt(const short* __restrict__ A,
                                               const short* __restrict__ Bm,
                                               short* __restrict__ C,
                                               int M, int N, int K) {
    int tid  = threadIdx.x;
    int wave = tid >> 6, lane = tid & 63;
    int quad = lane >> 4, l16 = lane & 15;
    int m0 = blockIdx.y * 128 + (wave >> 1) * 64;
    int n0 = blockIdx.x * 128 + (wave & 1) * 64;

    floatx4 acc[4][4];
    for (int i = 0; i < 4; i++)
        for (int j = 0; j < 4; j++) acc[i][j] = (floatx4){0.f, 0.f, 0.f, 0.f};

    const short* Ap = A + (long)(m0 + l16) * K + quad * 8;
    const short* Bp = Bm + (long)(n0 + l16) * K + quad * 8;

    for (int k0 = 0; k0 < K; k0 += 32) {
        short8 af[4], bfr[4];
        for (int i = 0; i < 4; i++)
            af[i] = *(const short8*)(Ap + (long)i * 16 * K + k0);
        for (int j = 0; j < 4; j++)
            bfr[j] = *(const short8*)(Bp + (long)j * 16 * K + k0);
        for (int i = 0; i < 4; i++)
            for (int j = 0; j < 4; j++)
                acc[i][j] = __builtin_amdgcn_mfma_f32_16x16x32_bf16(
                    af[i], bfr[j], acc[i][j], 0, 0, 0);
    }

    for (int i = 0; i < 4; i++)
        for (int j = 0; j < 4; j++) {
            int col = n0 + j * 16 + l16;
            for (int r = 0; r < 4; r++) {
                int row = m0 + i * 16 + quad * 4 + r;
                C[(long)row * N + col] = f2bf(acc[i][j][r]);
            }
        }
}

// Same as gemm_bt but fp32 output (final projection writes d_out directly).
__global__ __launch_bounds__(256) void gemm_bt_f32(const short* __restrict__ A,
                                                   const short* __restrict__ Bm,
                                                   float* __restrict__ C,
                                                   int M, int N, int K) {
    int tid  = threadIdx.x;
    int wave = tid >> 6, lane = tid & 63;
    int quad = lane >> 4, l16 = lane & 15;
    int m0 = blockIdx.y * 128 + (wave >> 1) * 64;
    int n0 = blockIdx.x * 128 + (wave & 1) * 64;

    floatx4 acc[4][4];
    for (int i = 0; i < 4; i++)
        for (int j = 0; j < 4; j++) acc[i][j] = (floatx4){0.f, 0.f, 0.f, 0.f};

    const short* Ap = A + (long)(m0 + l16) * K + quad * 8;
    const short* Bp = Bm + (long)(n0 + l16) * K + quad * 8;

    for (int k0 = 0; k0 < K; k0 += 32) {
        short8 af[4], bfr[4];
        for (int i = 0; i < 4; i++)
            af[i] = *(const short8*)(Ap + (long)i * 16 * K + k0);
        for (int j = 0; j < 4; j++)
            bfr[j] = *(const short8*)(Bp + (long)j * 16 * K + k0);
        for (int i = 0; i < 4; i++)
            for (int j = 0; j < 4; j++)
                acc[i][j] = __builtin_amdgcn_mfma_f32_16x16x32_bf16(
                    af[i], bfr[j], acc[i][j], 0, 0, 0);
    }

    for (int i = 0; i < 4; i++)
        for (int j = 0; j < 4; j++) {
            int col = n0 + j * 16 + l16;
            for (int r = 0; r < 4; r++) {
                int row = m0 + i * 16 + quad * 4 + r;
                C[(long)row * N + col] = acc[i][j][r];
            }
        }
}

// RoPE, faithful to reference quirk: angle row = HEAD index (cos[:nh]),
// broadcast over sequence. In-place on bf16 (B,S,nh,HD) buffer; fp32 tables.
__global__ void rope_kernel(short* __restrict__ t, const float* __restrict__ cosb,
                            const float* __restrict__ sinb, int nh, int total_pairs) {
    int gid = blockIdx.x * blockDim.x + threadIdx.x;
    if (gid >= total_pairs) return;
    int i = gid & 31;               // HD/2 = 32 pairs
    int h = (gid >> 5) % nh;        // head index selects the freq row
    float c = cosb[h * 32 + i];
    float s = sinb[h * 32 + i];
    float t0 = bf2f(t[2 * gid]);
    float t1 = bf2f(t[2 * gid + 1]);
    t[2 * gid]     = f2bf(t0 * c - t1 * s);
    t[2 * gid + 1] = f2bf(t0 * s + t1 * c);
}

// Fused causal GQA flash attention (bf16 in/out, fp32 softmax state).
// Grid: (S/64, H, B); block 256 = 4 waves, each wave 16 q-rows.
// xq/xk/xv live in d_out; out lives in ws — fully disjoint.
__global__ __launch_bounds__(256) void attn_kernel(const short* __restrict__ xq,
                                                   const short* __restrict__ xk,
                                                   const short* __restrict__ xv,
                                                   short* __restrict__ out) {
    __shared__ short vT[64][72];      // [d][key], transposed V tile (+pad)
    __shared__ short pT[4][16][72];   // per-wave P tile [row][key] (+pad)

    int qt = blockIdx.x, h = blockIdx.y, b = blockIdx.z;
    int kvh = h >> 2;                 // GQA repeat_interleave: head h <- kv h/4
    int tid = threadIdx.x, wave = tid >> 6, lane = tid & 63;
    int quad = lane >> 4, l16 = lane & 15;

    int qrow = qt * 64 + wave * 16 + l16;       // A-fragment row (Q and P)
    int crow = qt * 64 + wave * 16 + quad * 4;  // C-layout row base (+reg)

    // Q fragments for the whole kernel (HD=64 -> 2 k-steps)
    const short* qp = xq + (((long)b * kS + qrow) * kH + h) * kHD + quad * 8;
    short8 qf0 = *(const short8*)(qp);
    short8 qf1 = *(const short8*)(qp + 32);

    float m_run[4], l_run[4];
    floatx4 acc_o[4];
    for (int r = 0; r < 4; r++) { m_run[r] = kNegBig; l_run[r] = 0.f; }
    for (int nb = 0; nb < 4; nb++) acc_o[nb] = (floatx4){0.f, 0.f, 0.f, 0.f};

    for (int kt = 0; kt <= qt; kt++) {
        __syncthreads();   // protect vT against previous iteration's readers
        // Stage V transposed: vT[d][key]; 512 8-elem chunks over 256 threads.
        for (int c = tid; c < 512; c += 256) {
            int key = c >> 3;
            int db  = (c & 7) * 8;
            const short* vp = xv + (((long)b * kS + kt * 64 + key) * kKV + kvh) * kHD + db;
            short8 v = *(const short8*)vp;
            for (int i = 0; i < 8; i++) vT[db + i][key] = v[i];
        }
        __syncthreads();

        // Scores: Q(16xHD) x K^T(HDx64) as 4 key-blocks x 2 k-steps.
        floatx4 accs[4];
        for (int kb = 0; kb < 4; kb++) {
            int key = kt * 64 + kb * 16 + l16;
            const short* kp = xk + (((long)b * kS + key) * kKV + kvh) * kHD + quad * 8;
            short8 kf0 = *(const short8*)kp;
            short8 kf1 = *(const short8*)(kp + 32);
            accs[kb] = (floatx4){0.f, 0.f, 0.f, 0.f};
            accs[kb] = __builtin_amdgcn_mfma_f32_16x16x32_bf16(qf0, kf0, accs[kb], 0, 0, 0);
            accs[kb] = __builtin_amdgcn_mfma_f32_16x16x32_bf16(qf1, kf1, accs[kb], 0, 0, 0);
        }

        // Scale + causal mask + online softmax partials.
        float sv[4][4];   // [r][kb]
        for (int kb = 0; kb < 4; kb++)
            for (int r = 0; r < 4; r++) {
                float sc = accs[kb][r] * 0.125f;   // 1/sqrt(64)
                int kj = kt * 64 + kb * 16 + l16;
                if (kj > crow + r) sc = kNegBig;
                sv[r][kb] = sc;
            }

        float alpha[4], psum[4], mnew[4];
        for (int r = 0; r < 4; r++) {
            float mx = fmaxf(fmaxf(sv[r][0], sv[r][1]), fmaxf(sv[r][2], sv[r][3]));
            for (int off = 1; off < 16; off <<= 1) mx = fmaxf(mx, __shfl_xor(mx, off));
            mnew[r] = fmaxf(m_run[r], mx);
            alpha[r] = exp2f((m_run[r] - mnew[r]) * 1.44269504f);
            float ps = 0.f;
            for (int kb = 0; kb < 4; kb++) {
                float p = exp2f((sv[r][kb] - mnew[r]) * 1.44269504f);
                sv[r][kb] = p;
                ps += p;
            }
            for (int off = 1; off < 16; off <<= 1) ps += __shfl_xor(ps, off);
            psum[r] = ps;
        }

        // P -> LDS (C-layout to A-layout transpose through LDS, wave-private).
        for (int r = 0; r < 4; r++)
            for (int kb = 0; kb < 4; kb++)
                pT[wave][quad * 4 + r][kb * 16 + l16] = f2bf(sv[r][kb]);

        for (int r = 0; r < 4; r++) {
            m_run[r] = mnew[r];
            l_run[r] = l_run[r] * alpha[r] + psum[r];
        }
        for (int nb = 0; nb < 4; nb++)
            for (int r = 0; r < 4; r++) acc_o[nb][r] *= alpha[r];

        // PV: P(16x64) x V(64xHD), 2 k-steps (keys) x 4 n-blocks (d).
        short8 pf0 = *(const short8*)&pT[wave][l16][quad * 8];
        short8 pf1 = *(const short8*)&pT[wave][l16][32 + quad * 8];
        for (int nb = 0; nb < 4; nb++) {
            short8 vf0 = *(const short8*)&vT[nb * 16 + l16][quad * 8];
            short8 vf1 = *(const short8*)&vT[nb * 16 + l16][32 + quad * 8];
            acc_o[nb] = __builtin_amdgcn_mfma_f32_16x16x32_bf16(pf0, vf0, acc_o[nb], 0, 0, 0);
            acc_o[nb] = __builtin_amdgcn_mfma_f32_16x16x32_bf16(pf1, vf1, acc_o[nb], 0, 0, 0);
        }
    }

    // Epilogue: normalize and store (B,S,H,HD) bf16.
    for (int nb = 0; nb < 4; nb++)
        for (int r = 0; r < 4; r++) {
            int row = crow + r;
            float l = fmaxf(l_run[r], 1e-20f);   // defensive; l >= 1 in theory
            out[(((long)b * kS + row) * kH + h) * kHD + nb * 16 + l16] =
                f2bf(acc_o[nb][r] / l);
        }
}

extern "C" void kernel_launch(void* const* d_in, const int* in_sizes, int n_in,
                              void* d_out, int out_size, void* d_ws, size_t ws_size,
                              hipStream_t stream) {
    // setup_inputs order: x, freqs_cos, freqs_sin, mask, wq, wk, wv, wo
    // ALL inputs fp32 per the reference; output fp32 (4096x2048 = 32 MiB).
    const float* x  = (const float*)d_in[0];
    const float* fc = (const float*)d_in[1];
    const float* fs = (const float*)d_in[2];
    // d_in[3] = mask: structurally causal, implemented structurally.
    const float* wq = (const float*)d_in[4];
    const float* wk = (const float*)d_in[5];
    const float* wv = (const float*)d_in[6];
    const float* wo = (const float*)d_in[7];

    const int M = kB * kS;                // 4096
    const long MB = 1l << 20;

    // Buffer sizes (bytes): xb 16Mi, wqb/wob 8Mi, wkb/wvb 2Mi each,
    // xq 16Mi, xk/xv 4Mi each (4096x512 bf16!), ao 16Mi, out 32Mi fp32.
    //
    // ws (peak 24 MiB):                    d_out (32 MiB):
    //   [ 0,16) xb    — dead after V-proj    [ 0,16) xq bf16
    //   [16,24) wqb   — dead after Q-proj    [16,20) xk bf16
    //   [16,18) wkb   (over wqb)             [20,24) xv bf16
    //   [18,20) wvb   (over wqb)             final: all 32 MiB fp32 out
    //   [ 0,16) ao    (over xb)
    //   [16,24) wob   (over wkb/wvb)
    // Final GEMM reads ws only, writes d_out only (xq/xk/xv dead by then).
    char* ws = (char*)d_ws;
    short* xb  = (short*)(ws);
    short* wqb = (short*)(ws + 16 * MB);
    short* wkb = (short*)(ws + 16 * MB);
    short* wvb = (short*)(ws + 18 * MB);
    short* ao  = (short*)(ws);
    short* wob = (short*)(ws + 16 * MB);
    char*  dob = (char*)d_out;
    short* xq  = (short*)(dob);
    short* xk  = (short*)(dob + 16 * MB);
    short* xv  = (short*)(dob + 20 * MB);

    const int nX  = M * kD;         // 8388608
    const int nWq = kD * kD;        // 4194304
    const int nWk = kKV * kHD * kD; // 1048576

    cast_f2b<<<(nX / 4 + 255) / 256, 256, 0, stream>>>(x, xb, nX / 4);
    cast_f2b<<<(nWq / 4 + 255) / 256, 256, 0, stream>>>(wq, wqb, nWq / 4);
    gemm_bt<<<dim3(kD / 128, M / 128), 256, 0, stream>>>(xb, wqb, xq, M, kD, kD);

    cast_f2b<<<(nWk / 4 + 255) / 256, 256, 0, stream>>>(wk, wkb, nWk / 4);
    cast_f2b<<<(nWk / 4 + 255) / 256, 256, 0, stream>>>(wv, wvb, nWk / 4);
    gemm_bt<<<dim3((kKV * kHD) / 128, M / 128), 256, 0, stream>>>(xb, wkb, xk, M, kKV * kHD, kD);
    gemm_bt<<<dim3((kKV * kHD) / 128, M / 128), 256, 0, stream>>>(xb, wvb, xv, M, kKV * kHD, kD);

    rope_kernel<<<(M * kH * 32 + 255) / 256, 256, 0, stream>>>(
        xq, fc, fs, kH, M * kH * 32);
    rope_kernel<<<(M * kKV * 32 + 255) / 256, 256, 0, stream>>>(
        xk, fc, fs, kKV, M * kKV * 32);

    attn_kernel<<<dim3(kS / 64, kH, kB), 256, 0, stream>>>(xq, xk, xv, ao);

    cast_f2b<<<(nWq / 4 + 255) / 256, 256, 0, stream>>>(wo, wob, nWq / 4);
    gemm_bt_f32<<<dim3(kD / 128, M / 128), 256, 0, stream>>>(ao, wob, (float*)d_out, M, kD, kD);
}

// Round 6
// 483.811 us; speedup vs baseline: 1.4138x; 1.4138x over previous
//
#include <hip/hip_runtime.h>
#include <hip/hip_bf16.h>

// Problem constants
constexpr int kB  = 4;
constexpr int kS  = 1024;
constexpr int kD  = 2048;
constexpr int kH  = 32;
constexpr int kKV = 8;
constexpr int kHD = 64;

constexpr float kNegBig = -30000.0f;  // finite sentinel: no inf/overflow paths

typedef __attribute__((ext_vector_type(8))) short short8;   // 8 bf16 (4 VGPRs)
typedef __attribute__((ext_vector_type(4))) float floatx4;  // MFMA C/D

static __device__ __forceinline__ float bf2f(short v) {
    unsigned int u = ((unsigned int)(unsigned short)v) << 16;
    return __builtin_bit_cast(float, u);
}
static __device__ __forceinline__ short f2bf(float f) {
    unsigned int u = __builtin_bit_cast(unsigned int, f);
    unsigned int lsb = (u >> 16) & 1u;
    u += 0x7fffu + lsb;                       // round-to-nearest-even
    return (short)(u >> 16);
}

// Async global->LDS, 16 B per lane. LDS dest is wave-uniform base + lane*16.
static __device__ __forceinline__ void load_lds16(const short* g, short* l) {
    __builtin_amdgcn_global_load_lds(
        (const __attribute__((address_space(1))) unsigned int*)g,
        (__attribute__((address_space(3))) unsigned int*)l, 16, 0, 0);
}

// fp32 -> bf16, vectorized x4. n4 = element_count/4.
__global__ void cast_f2b(const float* __restrict__ in, short* __restrict__ outp, int n4) {
    int gid = blockIdx.x * blockDim.x + threadIdx.x;
    if (gid >= n4) return;
    float4 v = ((const float4*)in)[gid];
    short4 o;
    o.x = f2bf(v.x); o.y = f2bf(v.y); o.z = f2bf(v.z); o.w = f2bf(v.w);
    ((short4*)outp)[gid] = o;
}

// C[M,N] = A[M,K] * B[N,K]^T, bf16 in, fp32 acc, OT out (bf16 short or fp32).
// m97 structure: 128x128 tile, BK=32, global_load_lds width=16 staging,
// 2-barrier K-loop, ds_read_b128 fragments. Block = 4 waves in 2x2.
template <typename OT>
__global__ __launch_bounds__(256) void gemm_bt_lds(const short* __restrict__ A,
                                                   const short* __restrict__ Bm,
                                                   OT* __restrict__ C,
                                                   int M, int N, int K) {
    __shared__ short As[128 * 32];
    __shared__ short Bs[128 * 32];

    int tid  = threadIdx.x;
    int wave = tid >> 6, lane = tid & 63;
    int quad = lane >> 4, l16 = lane & 15;
    int wm = wave >> 1, wn = wave & 1;
    int m0 = blockIdx.y * 128, n0 = blockIdx.x * 128;

    floatx4 acc[4][4];
    for (int i = 0; i < 4; i++)
        for (int j = 0; j < 4; j++) acc[i][j] = (floatx4){0.f, 0.f, 0.f, 0.f};

    // Staging: 8 A-instr + 8 B-instr per tile; each wave issues 2+2.
    // Instr covers 16 rows: lane -> row lane>>2, kchunk (lane&3)*8 shorts.
    int srow = lane >> 2;           // 0..15
    int skc  = (lane & 3) * 8;      // 0,8,16,24

    for (int k0 = 0; k0 < K; k0 += 32) {
        __syncthreads();   // previous iteration's readers done
        for (int i = 0; i < 2; i++) {
            int r16 = wave * 32 + i * 16;
            load_lds16(A + (long)(m0 + r16 + srow) * K + k0 + skc, &As[r16 * 32]);
            load_lds16(Bm + (long)(n0 + r16 + srow) * K + k0 + skc, &Bs[r16 * 32]);
        }
        __syncthreads();   // drains vmcnt before barrier (compiler-emitted)

        short8 af[4], bfr[4];
        for (int i = 0; i < 4; i++)
            af[i] = *(const short8*)&As[(wm * 64 + i * 16 + l16) * 32 + quad * 8];
        for (int j = 0; j < 4; j++)
            bfr[j] = *(const short8*)&Bs[(wn * 64 + j * 16 + l16) * 32 + quad * 8];
        for (int i = 0; i < 4; i++)
            for (int j = 0; j < 4; j++)
                acc[i][j] = __builtin_amdgcn_mfma_f32_16x16x32_bf16(
                    af[i], bfr[j], acc[i][j], 0, 0, 0);
    }

    for (int i = 0; i < 4; i++)
        for (int j = 0; j < 4; j++) {
            int col = n0 + wn * 64 + j * 16 + l16;
            for (int r = 0; r < 4; r++) {
                int row = m0 + wm * 64 + i * 16 + quad * 4 + r;
                if constexpr (sizeof(OT) == 2)
                    C[(long)row * N + col] = f2bf(acc[i][j][r]);
                else
                    C[(long)row * N + col] = acc[i][j][r];
            }
        }
}

// RoPE for Q, faithful to reference quirk: angle row = HEAD index (cos[:nh]),
// broadcast over sequence. In-place on bf16 (M, H*HD) buffer; fp32 tables.
__global__ void rope_kernel(short* __restrict__ t, const float* __restrict__ cosb,
                            const float* __restrict__ sinb, int nh, int total_pairs) {
    int gid = blockIdx.x * blockDim.x + threadIdx.x;
    if (gid >= total_pairs) return;
    int i = gid & 31;               // HD/2 = 32 pairs
    int h = (gid >> 5) % nh;        // head index selects the freq row
    float c = cosb[h * 32 + i];
    float s = sinb[h * 32 + i];
    float t0 = bf2f(t[2 * gid]);
    float t1 = bf2f(t[2 * gid + 1]);
    t[2 * gid]     = f2bf(t0 * c - t1 * s);
    t[2 * gid + 1] = f2bf(t0 * s + t1 * c);
}

// RoPE for K inside fused KV buffer (M rows, row stride 1024, K = cols 0..511).
__global__ void rope_kv(short* __restrict__ t, const float* __restrict__ cosb,
                        const float* __restrict__ sinb, int total_pairs) {
    int gid = blockIdx.x * blockDim.x + threadIdx.x;
    if (gid >= total_pairs) return;
    int i = gid & 31;               // pair in head
    int h = (gid >> 5) & 7;         // KV head 0..7 (freq row = head, nh=8)
    int row = gid >> 8;             // 8 heads * 32 pairs per row
    float c = cosb[h * 32 + i];
    float s = sinb[h * 32 + i];
    long base = (long)row * 1024 + h * 64 + i * 2;
    float t0 = bf2f(t[base]);
    float t1 = bf2f(t[base + 1]);
    t[base]     = f2bf(t0 * c - t1 * s);
    t[base + 1] = f2bf(t0 * s + t1 * c);
}

// Fused causal GQA flash attention (bf16 in/out, fp32 softmax state).
// Grid: (S/64, H, B); block 256 = 4 waves, each wave 16 q-rows.
// Q rows stride 2048 (H*HD); K/V rows stride kvstride (fused KV buffer).
__global__ __launch_bounds__(256) void attn_kernel(const short* __restrict__ xq,
                                                   const short* __restrict__ xk,
                                                   const short* __restrict__ xv,
                                                   short* __restrict__ out,
                                                   int kvstride) {
    __shared__ short vT[64][72];      // [d][key], transposed V tile (+pad)
    __shared__ short pT[4][16][72];   // per-wave P tile [row][key] (+pad)

    int qt = blockIdx.x, h = blockIdx.y, b = blockIdx.z;
    int kvh = h >> 2;                 // GQA repeat_interleave: head h <- kv h/4
    int tid = threadIdx.x, wave = tid >> 6, lane = tid & 63;
    int quad = lane >> 4, l16 = lane & 15;

    int qrow = qt * 64 + wave * 16 + l16;       // A-fragment row (Q and P)
    int crow = qt * 64 + wave * 16 + quad * 4;  // C-layout row base (+reg)

    // Q fragments for the whole kernel (HD=64 -> 2 k-steps)
    const short* qp = xq + (((long)b * kS + qrow) * kH + h) * kHD + quad * 8;
    short8 qf0 = *(const short8*)(qp);
    short8 qf1 = *(const short8*)(qp + 32);

    float m_run[4], l_run[4];
    floatx4 acc_o[4];
    for (int r = 0; r < 4; r++) { m_run[r] = kNegBig; l_run[r] = 0.f; }
    for (int nb = 0; nb < 4; nb++) acc_o[nb] = (floatx4){0.f, 0.f, 0.f, 0.f};

    for (int kt = 0; kt <= qt; kt++) {
        __syncthreads();   // protect vT against previous iteration's readers
        // Stage V transposed: vT[d][key]; 512 8-elem chunks over 256 threads.
        for (int c = tid; c < 512; c += 256) {
            int key = c >> 3;
            int db  = (c & 7) * 8;
            const short* vp = xv + ((long)b * kS + kt * 64 + key) * kvstride
                              + kvh * kHD + db;
            short8 v = *(const short8*)vp;
            for (int i = 0; i < 8; i++) vT[db + i][key] = v[i];
        }
        __syncthreads();

        // Scores: Q(16xHD) x K^T(HDx64) as 4 key-blocks x 2 k-steps.
        floatx4 accs[4];
        for (int kb = 0; kb < 4; kb++) {
            int key = kt * 64 + kb * 16 + l16;
            const short* kp = xk + ((long)b * kS + key) * kvstride
                              + kvh * kHD + quad * 8;
            short8 kf0 = *(const short8*)kp;
            short8 kf1 = *(const short8*)(kp + 32);
            accs[kb] = (floatx4){0.f, 0.f, 0.f, 0.f};
            accs[kb] = __builtin_amdgcn_mfma_f32_16x16x32_bf16(qf0, kf0, accs[kb], 0, 0, 0);
            accs[kb] = __builtin_amdgcn_mfma_f32_16x16x32_bf16(qf1, kf1, accs[kb], 0, 0, 0);
        }

        // Scale + causal mask + online softmax partials.
        float sv[4][4];   // [r][kb]
        for (int kb = 0; kb < 4; kb++)
            for (int r = 0; r < 4; r++) {
                float sc = accs[kb][r] * 0.125f;   // 1/sqrt(64)
                int kj = kt * 64 + kb * 16 + l16;
                if (kj > crow + r) sc = kNegBig;
                sv[r][kb] = sc;
            }

        float alpha[4], psum[4], mnew[4];
        for (int r = 0; r < 4; r++) {
            float mx = fmaxf(fmaxf(sv[r][0], sv[r][1]), fmaxf(sv[r][2], sv[r][3]));
            for (int off = 1; off < 16; off <<= 1) mx = fmaxf(mx, __shfl_xor(mx, off));
            mnew[r] = fmaxf(m_run[r], mx);
            alpha[r] = exp2f((m_run[r] - mnew[r]) * 1.44269504f);
            float ps = 0.f;
            for (int kb = 0; kb < 4; kb++) {
                float p = exp2f((sv[r][kb] - mnew[r]) * 1.44269504f);
                sv[r][kb] = p;
                ps += p;
            }
            for (int off = 1; off < 16; off <<= 1) ps += __shfl_xor(ps, off);
            psum[r] = ps;
        }

        // P -> LDS (C-layout to A-layout transpose through LDS, wave-private).
        for (int r = 0; r < 4; r++)
            for (int kb = 0; kb < 4; kb++)
                pT[wave][quad * 4 + r][kb * 16 + l16] = f2bf(sv[r][kb]);

        for (int r = 0; r < 4; r++) {
            m_run[r] = mnew[r];
            l_run[r] = l_run[r] * alpha[r] + psum[r];
        }
        for (int nb = 0; nb < 4; nb++)
            for (int r = 0; r < 4; r++) acc_o[nb][r] *= alpha[r];

        // PV: P(16x64) x V(64xHD), 2 k-steps (keys) x 4 n-blocks (d).
        short8 pf0 = *(const short8*)&pT[wave][l16][quad * 8];
        short8 pf1 = *(const short8*)&pT[wave][l16][32 + quad * 8];
        for (int nb = 0; nb < 4; nb++) {
            short8 vf0 = *(const short8*)&vT[nb * 16 + l16][quad * 8];
            short8 vf1 = *(const short8*)&vT[nb * 16 + l16][32 + quad * 8];
            acc_o[nb] = __builtin_amdgcn_mfma_f32_16x16x32_bf16(pf0, vf0, acc_o[nb], 0, 0, 0);
            acc_o[nb] = __builtin_amdgcn_mfma_f32_16x16x32_bf16(pf1, vf1, acc_o[nb], 0, 0, 0);
        }
    }

    // Epilogue: normalize and store (B,S,H,HD) bf16.
    for (int nb = 0; nb < 4; nb++)
        for (int r = 0; r < 4; r++) {
            int row = crow + r;
            float l = fmaxf(l_run[r], 1e-20f);
            out[(((long)b * kS + row) * kH + h) * kHD + nb * 16 + l16] =
                f2bf(acc_o[nb][r] / l);
        }
}

extern "C" void kernel_launch(void* const* d_in, const int* in_sizes, int n_in,
                              void* d_out, int out_size, void* d_ws, size_t ws_size,
                              hipStream_t stream) {
    // setup_inputs order: x, freqs_cos, freqs_sin, mask, wq, wk, wv, wo
    const float* x  = (const float*)d_in[0];
    const float* fc = (const float*)d_in[1];
    const float* fs = (const float*)d_in[2];
    // d_in[3] = mask: structurally causal, implemented structurally.
    const float* wq = (const float*)d_in[4];
    const float* wk = (const float*)d_in[5];
    const float* wv = (const float*)d_in[6];
    const float* wo = (const float*)d_in[7];

    const int M = kB * kS;                // 4096
    const long MB = 1l << 20;

    // ws (peak 24 MiB, stream-ordered):   d_out (32 MiB):
    //   [ 0,16) xb   — dead after KV-proj   [ 0,16) xq bf16 (M x 2048)
    //   [16,24) wqb  — dead after Q-proj    [16,24) xkv bf16 (M x 1024: K|V)
    //   [16,20) wkvb (over wqb)             final: 32 MiB fp32 out
    //   [ 0,16) ao   (over xb)
    //   [16,24) wob  (over wkvb)
    char* ws = (char*)d_ws;
    short* xb   = (short*)(ws);
    short* wqb  = (short*)(ws + 16 * MB);
    short* wkvb = (short*)(ws + 16 * MB);
    short* ao   = (short*)(ws);
    short* wob  = (short*)(ws + 16 * MB);
    char*  dob  = (char*)d_out;
    short* xq   = (short*)(dob);
    short* xkv  = (short*)(dob + 16 * MB);

    const int nX  = M * kD;         // 8388608
    const int nWq = kD * kD;        // 4194304
    const int nWk = kKV * kHD * kD; // 1048576

    cast_f2b<<<(nX / 4 + 255) / 256, 256, 0, stream>>>(x, xb, nX / 4);
    cast_f2b<<<(nWq / 4 + 255) / 256, 256, 0, stream>>>(wq, wqb, nWq / 4);
    gemm_bt_lds<short><<<dim3(kD / 128, M / 128), 256, 0, stream>>>(
        xb, wqb, xq, M, kD, kD);

    // Fused KV weights: rows 0..511 = wk, rows 512..1023 = wv.
    cast_f2b<<<(nWk / 4 + 255) / 256, 256, 0, stream>>>(wk, wkvb, nWk / 4);
    cast_f2b<<<(nWk / 4 + 255) / 256, 256, 0, stream>>>(wv, wkvb + nWk, nWk / 4);
    gemm_bt_lds<short><<<dim3(1024 / 128, M / 128), 256, 0, stream>>>(
        xb, wkvb, xkv, M, 1024, kD);

    rope_kernel<<<(M * kH * 32 + 255) / 256, 256, 0, stream>>>(
        xq, fc, fs, kH, M * kH * 32);
    rope_kv<<<(M * kKV * 32 + 255) / 256, 256, 0, stream>>>(
        xkv, fc, fs, M * kKV * 32);

    attn_kernel<<<dim3(kS / 64, kH, kB), 256, 0, stream>>>(
        xq, xkv, xkv + 512, ao, 1024);

    cast_f2b<<<(nWq / 4 + 255) / 256, 256, 0, stream>>>(wo, wob, nWq / 4);
    gemm_bt_lds<float><<<dim3(kD / 128, M / 128), 256, 0, stream>>>(
        ao, wob, (float*)d_out, M, kD, kD);
}

// Round 7
// 453.160 us; speedup vs baseline: 1.5094x; 1.0676x over previous
//
#include <hip/hip_runtime.h>
#include <hip/hip_bf16.h>

// Problem constants
constexpr int kB  = 4;
constexpr int kS  = 1024;
constexpr int kD  = 2048;
constexpr int kH  = 32;
constexpr int kKV = 8;
constexpr int kHD = 64;

constexpr float kNegBig = -30000.0f;   // finite sentinel: no inf/overflow paths
constexpr float kC = 0.125f * 1.44269504f;  // 1/sqrt(HD) folded into exp2

typedef __attribute__((ext_vector_type(8))) short short8;   // 8 bf16 (4 VGPRs)
typedef __attribute__((ext_vector_type(4))) float floatx4;  // MFMA C/D

static __device__ __forceinline__ float bf2f(short v) {
    unsigned int u = ((unsigned int)(unsigned short)v) << 16;
    return __builtin_bit_cast(float, u);
}
static __device__ __forceinline__ short f2bf(float f) {
    unsigned int u = __builtin_bit_cast(unsigned int, f);
    unsigned int lsb = (u >> 16) & 1u;
    u += 0x7fffu + lsb;                       // round-to-nearest-even
    return (short)(u >> 16);
}
// Cheap pack for P in [0,1]: round-half-up (bias ~2^-9 relative, harmless).
static __device__ __forceinline__ short f2bf_fast(float f) {
    unsigned int u = __builtin_bit_cast(unsigned int, f);
    return (short)((u + 0x8000u) >> 16);
}

// Async global->LDS, 16 B per lane. LDS dest is wave-uniform base + lane*16.
static __device__ __forceinline__ void load_lds16(const short* g, short* l) {
    __builtin_amdgcn_global_load_lds(
        (const __attribute__((address_space(1))) unsigned int*)g,
        (__attribute__((address_space(3))) unsigned int*)l, 16, 0, 0);
}

// fp32 -> bf16, vectorized x4. n4 = element_count/4.
__global__ void cast_f2b(const float* __restrict__ in, short* __restrict__ outp, int n4) {
    int gid = blockIdx.x * blockDim.x + threadIdx.x;
    if (gid >= n4) return;
    float4 v = ((const float4*)in)[gid];
    short4 o;
    o.x = f2bf(v.x); o.y = f2bf(v.y); o.z = f2bf(v.z); o.w = f2bf(v.w);
    ((short4*)outp)[gid] = o;
}

// C[M,N] = A[M,K] * B[N,K]^T, bf16 in, fp32 acc, OT out (bf16 short or fp32).
// m97 structure: 128x128 tile, BK=32, global_load_lds width=16 staging,
// 2-barrier K-loop, ds_read_b128 fragments. Block = 4 waves in 2x2.
template <typename OT>
__global__ __launch_bounds__(256) void gemm_bt_lds(const short* __restrict__ A,
                                                   const short* __restrict__ Bm,
                                                   OT* __restrict__ C,
                                                   int M, int N, int K) {
    __shared__ short As[128 * 32];
    __shared__ short Bs[128 * 32];

    int tid  = threadIdx.x;
    int wave = tid >> 6, lane = tid & 63;
    int quad = lane >> 4, l16 = lane & 15;
    int wm = wave >> 1, wn = wave & 1;
    int m0 = blockIdx.y * 128, n0 = blockIdx.x * 128;

    floatx4 acc[4][4];
    for (int i = 0; i < 4; i++)
        for (int j = 0; j < 4; j++) acc[i][j] = (floatx4){0.f, 0.f, 0.f, 0.f};

    int srow = lane >> 2;           // 0..15
    int skc  = (lane & 3) * 8;      // 0,8,16,24

    for (int k0 = 0; k0 < K; k0 += 32) {
        __syncthreads();
        for (int i = 0; i < 2; i++) {
            int r16 = wave * 32 + i * 16;
            load_lds16(A + (long)(m0 + r16 + srow) * K + k0 + skc, &As[r16 * 32]);
            load_lds16(Bm + (long)(n0 + r16 + srow) * K + k0 + skc, &Bs[r16 * 32]);
        }
        __syncthreads();

        short8 af[4], bfr[4];
        for (int i = 0; i < 4; i++)
            af[i] = *(const short8*)&As[(wm * 64 + i * 16 + l16) * 32 + quad * 8];
        for (int j = 0; j < 4; j++)
            bfr[j] = *(const short8*)&Bs[(wn * 64 + j * 16 + l16) * 32 + quad * 8];
        for (int i = 0; i < 4; i++)
            for (int j = 0; j < 4; j++)
                acc[i][j] = __builtin_amdgcn_mfma_f32_16x16x32_bf16(
                    af[i], bfr[j], acc[i][j], 0, 0, 0);
    }

    for (int i = 0; i < 4; i++)
        for (int j = 0; j < 4; j++) {
            int col = n0 + wn * 64 + j * 16 + l16;
            for (int r = 0; r < 4; r++) {
                int row = m0 + wm * 64 + i * 16 + quad * 4 + r;
                if constexpr (sizeof(OT) == 2)
                    C[(long)row * N + col] = f2bf(acc[i][j][r]);
                else
                    C[(long)row * N + col] = acc[i][j][r];
            }
        }
}

// RoPE for Q, faithful to reference quirk: angle row = HEAD index (cos[:nh]),
// broadcast over sequence. In-place on bf16 (M, H*HD) buffer; fp32 tables.
__global__ void rope_kernel(short* __restrict__ t, const float* __restrict__ cosb,
                            const float* __restrict__ sinb, int nh, int total_pairs) {
    int gid = blockIdx.x * blockDim.x + threadIdx.x;
    if (gid >= total_pairs) return;
    int i = gid & 31;
    int h = (gid >> 5) % nh;
    float c = cosb[h * 32 + i];
    float s = sinb[h * 32 + i];
    float t0 = bf2f(t[2 * gid]);
    float t1 = bf2f(t[2 * gid + 1]);
    t[2 * gid]     = f2bf(t0 * c - t1 * s);
    t[2 * gid + 1] = f2bf(t0 * s + t1 * c);
}

// RoPE for K inside fused KV buffer (M rows, row stride 1024, K = cols 0..511).
__global__ void rope_kv(short* __restrict__ t, const float* __restrict__ cosb,
                        const float* __restrict__ sinb, int total_pairs) {
    int gid = blockIdx.x * blockDim.x + threadIdx.x;
    if (gid >= total_pairs) return;
    int i = gid & 31;
    int h = (gid >> 5) & 7;
    int row = gid >> 8;
    float c = cosb[h * 32 + i];
    float s = sinb[h * 32 + i];
    long base = (long)row * 1024 + h * 64 + i * 2;
    float t0 = bf2f(t[base]);
    float t1 = bf2f(t[base + 1]);
    t[base]     = f2bf(t0 * c - t1 * s);
    t[base + 1] = f2bf(t0 * s + t1 * c);
}

// Fused causal GQA flash attention (bf16 in/out, fp32 softmax state).
// Grid: (S/64, H, B); block 256 = 4 waves, each wave 16 q-rows.
// Round-7: conflict-free V staging, reg-prefetched V, K loads hoisted before
// the barrier, ones-MFMA row-sum (no sum shuffles), diagonal-only masking,
// scale folded into exp2 constant, heavy q-tiles launched first.
__global__ __launch_bounds__(256) void attn_kernel(const short* __restrict__ xq,
                                                   const short* __restrict__ xk,
                                                   const short* __restrict__ xv,
                                                   short* __restrict__ out,
                                                   int kvstride) {
    __shared__ short vT[64][72];      // [d][key], transposed V tile (+pad)
    __shared__ short pT[4][16][72];   // per-wave P tile [row][key] (+pad)

    int qt = gridDim.x - 1 - blockIdx.x;   // heavy blocks first (tail balance)
    int h = blockIdx.y, b = blockIdx.z;
    int kvh = h >> 2;                 // GQA repeat_interleave: head h <- kv h/4
    int tid = threadIdx.x, wave = tid >> 6, lane = tid & 63;
    int quad = lane >> 4, l16 = lane & 15;

    int qrow = qt * 64 + wave * 16 + l16;       // A-fragment row (Q and P)
    int crow = qt * 64 + wave * 16 + quad * 4;  // C-layout row base (+reg)

    // Q fragments for the whole kernel (HD=64 -> 2 k-steps)
    const short* qp = xq + (((long)b * kS + qrow) * kH + h) * kHD + quad * 8;
    short8 qf0 = *(const short8*)(qp);
    short8 qf1 = *(const short8*)(qp + 32);

    // all-ones bf16 B-fragment: mfma(P, ones) puts row-sum(P) in every column
    short8 ones;
    for (int i = 0; i < 8; i++) ones[i] = (short)0x3F80;

    float m_run[4];
    floatx4 acc_l = (floatx4){0.f, 0.f, 0.f, 0.f};   // online l per row
    floatx4 acc_o[4];
    for (int r = 0; r < 4; r++) m_run[r] = kNegBig;
    for (int nb = 0; nb < 4; nb++) acc_o[nb] = (floatx4){0.f, 0.f, 0.f, 0.f};

    // V staging map: thread covers (key=tid&63, d in [8w,8w+8) and [8w+32,8w+40))
    // LDS writes have consecutive keys across lanes -> 2-way banks (free).
    int vkey = tid & 63;
    int vdb  = (tid >> 6) * 8;
    const short* vbase = xv + (long)b * kS * kvstride + kvh * kHD;

    // prologue: prefetch V tile 0 into registers
    const short* vp0 = vbase + (long)vkey * kvstride + vdb;
    short8 vr0 = *(const short8*)(vp0);
    short8 vr1 = *(const short8*)(vp0 + 32);

    const short* kbase0 = xk + (long)b * kS * kvstride + kvh * kHD;

    for (int kt = 0; kt <= qt; kt++) {
        // K fragments for this tile: global->VGPR, independent of LDS/barrier.
        short8 kf[4][2];
        const short* kbase = kbase0 + (long)kt * 64 * kvstride;
        for (int kb = 0; kb < 4; kb++) {
            const short* kp = kbase + (long)(kb * 16 + l16) * kvstride + quad * 8;
            kf[kb][0] = *(const short8*)kp;
            kf[kb][1] = *(const short8*)(kp + 32);
        }

        __syncthreads();   // previous iteration's vT readers done
        for (int i = 0; i < 8; i++) {
            vT[vdb + i][vkey]      = vr0[i];
            vT[vdb + 32 + i][vkey] = vr1[i];
        }
        if (kt < qt) {     // prefetch next V tile (overlaps compute below)
            const short* vp = vbase + (long)((kt + 1) * 64 + vkey) * kvstride + vdb;
            vr0 = *(const short8*)(vp);
            vr1 = *(const short8*)(vp + 32);
        }
        __syncthreads();   // vT ready

        // Scores (raw, unscaled): Q(16xHD) x K^T(HDx64), 4 key-blocks.
        floatx4 accs[4];
        for (int kb = 0; kb < 4; kb++) {
            accs[kb] = (floatx4){0.f, 0.f, 0.f, 0.f};
            accs[kb] = __builtin_amdgcn_mfma_f32_16x16x32_bf16(qf0, kf[kb][0], accs[kb], 0, 0, 0);
            accs[kb] = __builtin_amdgcn_mfma_f32_16x16x32_bf16(qf1, kf[kb][1], accs[kb], 0, 0, 0);
        }

        float sv[4][4];   // [r][kb], raw scores
        for (int kb = 0; kb < 4; kb++)
            for (int r = 0; r < 4; r++) sv[r][kb] = accs[kb][r];

        if (kt == qt) {    // causal mask: only the diagonal tile needs it
            for (int kb = 0; kb < 4; kb++)
                for (int r = 0; r < 4; r++) {
                    int kj = kt * 64 + kb * 16 + l16;
                    if (kj > crow + r) sv[r][kb] = kNegBig;
                }
        }

        // Online softmax: exact 16-lane max; sum comes from the ones-MFMA.
        float alpha[4];
        for (int r = 0; r < 4; r++) {
            float mx = fmaxf(fmaxf(sv[r][0], sv[r][1]), fmaxf(sv[r][2], sv[r][3]));
            for (int off = 1; off < 16; off <<= 1) mx = fmaxf(mx, __shfl_xor(mx, off));
            float mnew = fmaxf(m_run[r], mx);
            alpha[r] = exp2f((m_run[r] - mnew) * kC);
            m_run[r] = mnew;
            for (int kb = 0; kb < 4; kb++)
                sv[r][kb] = exp2f((sv[r][kb] - mnew) * kC);
        }

        // P -> LDS (C-layout to A-layout transpose, wave-private).
        for (int r = 0; r < 4; r++)
            for (int kb = 0; kb < 4; kb++)
                pT[wave][quad * 4 + r][kb * 16 + l16] = f2bf_fast(sv[r][kb]);

        for (int r = 0; r < 4; r++) {
            acc_l[r] *= alpha[r];
            for (int nb = 0; nb < 4; nb++) acc_o[nb][r] *= alpha[r];
        }

        // PV + row-sum: P(16x64) x [V(64xHD) | ones]
        short8 pf0 = *(const short8*)&pT[wave][l16][quad * 8];
        short8 pf1 = *(const short8*)&pT[wave][l16][32 + quad * 8];
        acc_l = __builtin_amdgcn_mfma_f32_16x16x32_bf16(pf0, ones, acc_l, 0, 0, 0);
        acc_l = __builtin_amdgcn_mfma_f32_16x16x32_bf16(pf1, ones, acc_l, 0, 0, 0);
        for (int nb = 0; nb < 4; nb++) {
            short8 vf0 = *(const short8*)&vT[nb * 16 + l16][quad * 8];
            short8 vf1 = *(const short8*)&vT[nb * 16 + l16][32 + quad * 8];
            acc_o[nb] = __builtin_amdgcn_mfma_f32_16x16x32_bf16(pf0, vf0, acc_o[nb], 0, 0, 0);
            acc_o[nb] = __builtin_amdgcn_mfma_f32_16x16x32_bf16(pf1, vf1, acc_o[nb], 0, 0, 0);
        }
    }

    // Epilogue: normalize and store (B,S,H,HD) bf16.
    for (int r = 0; r < 4; r++) {
        float inv = 1.0f / fmaxf(acc_l[r], 1e-20f);
        int row = crow + r;
        for (int nb = 0; nb < 4; nb++)
            out[(((long)b * kS + row) * kH + h) * kHD + nb * 16 + l16] =
                f2bf(acc_o[nb][r] * inv);
    }
}

extern "C" void kernel_launch(void* const* d_in, const int* in_sizes, int n_in,
                              void* d_out, int out_size, void* d_ws, size_t ws_size,
                              hipStream_t stream) {
    // setup_inputs order: x, freqs_cos, freqs_sin, mask, wq, wk, wv, wo
    const float* x  = (const float*)d_in[0];
    const float* fc = (const float*)d_in[1];
    const float* fs = (const float*)d_in[2];
    // d_in[3] = mask: structurally causal, implemented structurally.
    const float* wq = (const float*)d_in[4];
    const float* wk = (const float*)d_in[5];
    const float* wv = (const float*)d_in[6];
    const float* wo = (const float*)d_in[7];

    const int M = kB * kS;                // 4096
    const long MB = 1l << 20;

    // ws (peak 24 MiB, stream-ordered):   d_out (32 MiB):
    //   [ 0,16) xb   — dead after KV-proj   [ 0,16) xq bf16 (M x 2048)
    //   [16,24) wqb  — dead after Q-proj    [16,24) xkv bf16 (M x 1024: K|V)
    //   [16,20) wkvb (over wqb)             final: 32 MiB fp32 out
    //   [ 0,16) ao   (over xb)
    //   [16,24) wob  (over wkvb)
    char* ws = (char*)d_ws;
    short* xb   = (short*)(ws);
    short* wqb  = (short*)(ws + 16 * MB);
    short* wkvb = (short*)(ws + 16 * MB);
    short* ao   = (short*)(ws);
    short* wob  = (short*)(ws + 16 * MB);
    char*  dob  = (char*)d_out;
    short* xq   = (short*)(dob);
    short* xkv  = (short*)(dob + 16 * MB);

    const int nX  = M * kD;         // 8388608
    const int nWq = kD * kD;        // 4194304
    const int nWk = kKV * kHD * kD; // 1048576

    cast_f2b<<<(nX / 4 + 255) / 256, 256, 0, stream>>>(x, xb, nX / 4);
    cast_f2b<<<(nWq / 4 + 255) / 256, 256, 0, stream>>>(wq, wqb, nWq / 4);
    gemm_bt_lds<short><<<dim3(kD / 128, M / 128), 256, 0, stream>>>(
        xb, wqb, xq, M, kD, kD);

    // Fused KV weights: rows 0..511 = wk, rows 512..1023 = wv.
    cast_f2b<<<(nWk / 4 + 255) / 256, 256, 0, stream>>>(wk, wkvb, nWk / 4);
    cast_f2b<<<(nWk / 4 + 255) / 256, 256, 0, stream>>>(wv, wkvb + nWk, nWk / 4);
    gemm_bt_lds<short><<<dim3(1024 / 128, M / 128), 256, 0, stream>>>(
        xb, wkvb, xkv, M, 1024, kD);

    rope_kernel<<<(M * kH * 32 + 255) / 256, 256, 0, stream>>>(
        xq, fc, fs, kH, M * kH * 32);
    rope_kv<<<(M * kKV * 32 + 255) / 256, 256, 0, stream>>>(
        xkv, fc, fs, M * kKV * 32);

    attn_kernel<<<dim3(kS / 64, kH, kB), 256, 0, stream>>>(
        xq, xkv, xkv + 512, ao, 1024);

    cast_f2b<<<(nWq / 4 + 255) / 256, 256, 0, stream>>>(wo, wob, nWq / 4);
    gemm_bt_lds<float><<<dim3(kD / 128, M / 128), 256, 0, stream>>>(
        ao, wob, (float*)d_out, M, kD, kD);
}